// Round 2
// baseline (18565.813 us; speedup 1.0000x reference)
//
#include <hip/hip_runtime.h>
#include <stdint.h>
#include <math.h>

#define D_MODEL 1536
#define NH 12
#define HD 128
#define NL 12
#define SEQ 1024
#define D3 4608
#define D4 6144
#define SCALE 0.025515518153991442f  // 1/sqrt(1536)

// ------------------------------------------------------------- embed
__global__ __launch_bounds__(256)
void embed_kernel(const int* __restrict__ idx, const float* __restrict__ tok,
                  const float* __restrict__ pos, float* __restrict__ x) {
  int i = blockIdx.x * 256 + threadIdx.x;   // over SEQ*D_MODEL
  int s = i / D_MODEL;
  int d = i - s * D_MODEL;
  // faithful quirk: pos_emb[:1] broadcasts -> every position gets pos row 0
  x[i] = tok[(size_t)idx[s] * D_MODEL + d] + pos[d];
}

// ------------------------------------------------------------- f32 GEMM
// C[M,N] = act(A[M,K] @ B[K,N] + bias[N] (+ res)); tile (RB*64) x 128, BK=16.
template<int RB, bool RELU, bool RES>
__global__ __launch_bounds__(256)
void gemm_kernel(const float* __restrict__ A, const float* __restrict__ B,
                 const float* __restrict__ bias, const float* __restrict__ res,
                 float* __restrict__ C, int M, int N, int K) {
  __shared__ float As[16][RB * 64 + 4];   // transposed: [k][m]
  __shared__ float Bs[16][132];           // [k][n]
  const int tid = threadIdx.x;
  const int bm = blockIdx.y * (RB * 64);
  const int bn = blockIdx.x << 7;
  const int tr = tid & 15, tc = tid >> 4;
  const int tm = tr << 2, tn = tc << 2;
  const int sar = tid >> 2;          // A row in tile (+ rb*64)
  const int sac = (tid & 3) << 2;    // k chunk (float4)
  const int sbr = tid >> 5;          // B k-row (and +8)
  const int sbc = (tid & 31) << 2;   // B col chunk

  float acc[RB * 4][8];
#pragma unroll
  for (int i = 0; i < RB * 4; i++)
#pragma unroll
    for (int j = 0; j < 8; j++) acc[i][j] = 0.f;

  for (int k0 = 0; k0 < K; k0 += 16) {
    __syncthreads();
#pragma unroll
    for (int rb = 0; rb < RB; rb++) {
      float4 a = *(const float4*)&A[(size_t)(bm + rb * 64 + sar) * K + k0 + sac];
      As[sac + 0][rb * 64 + sar] = a.x;
      As[sac + 1][rb * 64 + sar] = a.y;
      As[sac + 2][rb * 64 + sar] = a.z;
      As[sac + 3][rb * 64 + sar] = a.w;
    }
    *(float4*)&Bs[sbr][sbc]     = *(const float4*)&B[(size_t)(k0 + sbr) * N + bn + sbc];
    *(float4*)&Bs[8 + sbr][sbc] = *(const float4*)&B[(size_t)(k0 + 8 + sbr) * N + bn + sbc];
    __syncthreads();
#pragma unroll
    for (int kk = 0; kk < 16; kk++) {
      float av[RB * 4], bv[8];
#pragma unroll
      for (int rb = 0; rb < RB; rb++) {
        float4 t = *(const float4*)&As[kk][rb * 64 + tm];
        av[rb*4+0] = t.x; av[rb*4+1] = t.y; av[rb*4+2] = t.z; av[rb*4+3] = t.w;
      }
      float4 t0 = *(const float4*)&Bs[kk][tn];
      float4 t1 = *(const float4*)&Bs[kk][64 + tn];
      bv[0]=t0.x; bv[1]=t0.y; bv[2]=t0.z; bv[3]=t0.w;
      bv[4]=t1.x; bv[5]=t1.y; bv[6]=t1.z; bv[7]=t1.w;
#pragma unroll
      for (int i = 0; i < RB * 4; i++)
#pragma unroll
        for (int j = 0; j < 8; j++)
          acc[i][j] = fmaf(av[i], bv[j], acc[i][j]);
    }
  }
#pragma unroll
  for (int i = 0; i < RB * 4; i++) {
    const int row = bm + (i >> 2) * 64 + tm + (i & 3);
#pragma unroll
    for (int jb = 0; jb < 2; jb++) {
      const int col = bn + jb * 64 + tn;
      float4 r;
      r.x = acc[i][jb*4+0] + bias[col+0];
      r.y = acc[i][jb*4+1] + bias[col+1];
      r.z = acc[i][jb*4+2] + bias[col+2];
      r.w = acc[i][jb*4+3] + bias[col+3];
      if constexpr (RES) {
        float4 rr = *(const float4*)&res[(size_t)row * N + col];
        r.x += rr.x; r.y += rr.y; r.z += rr.z; r.w += rr.w;
      }
      if constexpr (RELU) {
        r.x = fmaxf(r.x, 0.f); r.y = fmaxf(r.y, 0.f);
        r.z = fmaxf(r.z, 0.f); r.w = fmaxf(r.w, 0.f);
      }
      *(float4*)&C[(size_t)row * N + col] = r;
    }
  }
}

// ------------------------------------------------------------- scores (f32)
// scores[h][i][j] = (j<=i) ? SCALE * q_i . k_j : -1e30
__global__ __launch_bounds__(256)
void scores_kernel(const float* __restrict__ qkv, float* __restrict__ scores) {
  __shared__ float Qs[16][132];   // [k][i]
  __shared__ float Ks[16][132];   // [k][j]
  const int tid = threadIdx.x;
  const int h = blockIdx.z;
  const int bi = blockIdx.y << 7, bj = blockIdx.x << 7;
  const int tr = tid & 15, tc = tid >> 4;
  const int tm = tr << 2, tn = tc << 2;
  const int sar = tid >> 2;
  const int sac = (tid & 3) << 2;
  const float* Q = qkv + h * HD;
  const float* Kp = qkv + D_MODEL + h * HD;

  float acc[8][8];
#pragma unroll
  for (int i = 0; i < 8; i++)
#pragma unroll
    for (int j = 0; j < 8; j++) acc[i][j] = 0.f;

  for (int k0 = 0; k0 < HD; k0 += 16) {
    __syncthreads();
#pragma unroll
    for (int rb = 0; rb < 2; rb++) {
      float4 a = *(const float4*)&Q[(size_t)(bi + rb * 64 + sar) * D3 + k0 + sac];
      Qs[sac + 0][rb * 64 + sar] = a.x;
      Qs[sac + 1][rb * 64 + sar] = a.y;
      Qs[sac + 2][rb * 64 + sar] = a.z;
      Qs[sac + 3][rb * 64 + sar] = a.w;
      float4 b = *(const float4*)&Kp[(size_t)(bj + rb * 64 + sar) * D3 + k0 + sac];
      Ks[sac + 0][rb * 64 + sar] = b.x;
      Ks[sac + 1][rb * 64 + sar] = b.y;
      Ks[sac + 2][rb * 64 + sar] = b.z;
      Ks[sac + 3][rb * 64 + sar] = b.w;
    }
    __syncthreads();
#pragma unroll
    for (int kk = 0; kk < 16; kk++) {
      float av[8], bv[8];
#pragma unroll
      for (int rb = 0; rb < 2; rb++) {
        float4 t = *(const float4*)&Qs[kk][rb * 64 + tm];
        av[rb*4+0] = t.x; av[rb*4+1] = t.y; av[rb*4+2] = t.z; av[rb*4+3] = t.w;
      }
      float4 t0 = *(const float4*)&Ks[kk][tn];
      float4 t1 = *(const float4*)&Ks[kk][64 + tn];
      bv[0]=t0.x; bv[1]=t0.y; bv[2]=t0.z; bv[3]=t0.w;
      bv[4]=t1.x; bv[5]=t1.y; bv[6]=t1.z; bv[7]=t1.w;
#pragma unroll
      for (int i = 0; i < 8; i++)
#pragma unroll
        for (int j = 0; j < 8; j++)
          acc[i][j] = fmaf(av[i], bv[j], acc[i][j]);
    }
  }
  float* S = scores + (size_t)h * SEQ * SEQ;
#pragma unroll
  for (int i = 0; i < 8; i++) {
    const int row = bi + (i >> 2) * 64 + tm + (i & 3);
#pragma unroll
    for (int jb = 0; jb < 2; jb++) {
      const int col0 = bj + jb * 64 + tn;
      float4 r;
      r.x = (col0 + 0 <= row) ? acc[i][jb*4+0] * SCALE : -1e30f;
      r.y = (col0 + 1 <= row) ? acc[i][jb*4+1] * SCALE : -1e30f;
      r.z = (col0 + 2 <= row) ? acc[i][jb*4+2] * SCALE : -1e30f;
      r.w = (col0 + 3 <= row) ? acc[i][jb*4+3] * SCALE : -1e30f;
      *(float4*)&S[(size_t)row * SEQ + col0] = r;
    }
  }
}

// ------------------------------------------------------------- column stats
// softmax over QUERY axis: per column k, M[k]=max_q s, Z[k]=sum_q exp(s-M)
__global__ __launch_bounds__(256)
void colstatA_kernel(const float* __restrict__ scores, float* __restrict__ pstats) {
  const int b = blockIdx.x;          // h*32 + cc*8 + qc
  const int h = b >> 5;
  const int cc = (b >> 3) & 3;
  const int qc = b & 7;
  const int c = (cc << 8) + threadIdx.x;
  const int q0 = qc << 7;
  const float* Sc = scores + (size_t)h * SEQ * SEQ + c;
  float m = -1e30f, z = 0.f;
  for (int q = q0; q < q0 + 128; q++) {
    if (q >= c) {   // entries q<c are masked
      float sv = Sc[(size_t)q * SEQ];
      float mn = fmaxf(m, sv);
      z = z * expf(m - mn) + expf(sv - mn);
      m = mn;
    }
  }
  pstats[(size_t)((h * 8 + qc) * 2 + 0) * 1024 + c] = m;
  pstats[(size_t)((h * 8 + qc) * 2 + 1) * 1024 + c] = z;
}

__global__ __launch_bounds__(256)
void colstatB_kernel(const float* __restrict__ pstats, float* __restrict__ stats) {
  const int i = blockIdx.x * 256 + threadIdx.x;  // h*1024 + c
  const int h = i >> 10, c = i & 1023;
  float m = -1e30f;
#pragma unroll
  for (int qc = 0; qc < 8; qc++)
    m = fmaxf(m, pstats[(size_t)((h * 8 + qc) * 2 + 0) * 1024 + c]);
  float z = 0.f;
#pragma unroll
  for (int qc = 0; qc < 8; qc++) {
    float pm = pstats[(size_t)((h * 8 + qc) * 2 + 0) * 1024 + c];
    float pz = pstats[(size_t)((h * 8 + qc) * 2 + 1) * 1024 + c];
    z += pz * expf(pm - m);   // pm=-1e30 chunks: pz=0, exp=0
  }
  stats[h * 2048 + c] = m;
  stats[h * 2048 + 1024 + c] = 1.f / z;
}

// ------------------------------------------------------------- attn @ V (f32)
// o[q][h*HD+d] = sum_k exp(s[q,k]-M[k])*rZ[k] * v[k][d];  64-row tiles
__global__ __launch_bounds__(256)
void av_kernel(const float* __restrict__ qkv, const float* __restrict__ scores,
               const float* __restrict__ stats, float* __restrict__ o) {
  __shared__ float Ps[16][68];    // [k][q]
  __shared__ float Vs[16][132];   // [k][d]
  const int tid = threadIdx.x;
  const int h = blockIdx.z;
  const int bm = blockIdx.y << 6;
  const int tr = tid & 15, tc = tid >> 4;
  const int tm = tr << 2, tn = tc << 2;
  const int sar = tid >> 2;
  const int sac = (tid & 3) << 2;
  const int sbr = tid >> 5;
  const int sbc = (tid & 31) << 2;
  const float* S = scores + (size_t)h * SEQ * SEQ;
  const float* Mh = stats + h * 2048;
  const float* Rh = Mh + 1024;
  const float* V = qkv + 2 * D_MODEL + h * HD;

  float acc[4][8];
#pragma unroll
  for (int i = 0; i < 4; i++)
#pragma unroll
    for (int j = 0; j < 8; j++) acc[i][j] = 0.f;

  for (int k0 = 0; k0 < SEQ; k0 += 16) {
    __syncthreads();
    {
      float4 s4 = *(const float4*)&S[(size_t)(bm + sar) * SEQ + k0 + sac];
      Ps[sac + 0][sar] = expf(s4.x - Mh[k0 + sac + 0]) * Rh[k0 + sac + 0];
      Ps[sac + 1][sar] = expf(s4.y - Mh[k0 + sac + 1]) * Rh[k0 + sac + 1];
      Ps[sac + 2][sar] = expf(s4.z - Mh[k0 + sac + 2]) * Rh[k0 + sac + 2];
      Ps[sac + 3][sar] = expf(s4.w - Mh[k0 + sac + 3]) * Rh[k0 + sac + 3];
    }
    *(float4*)&Vs[sbr][sbc]     = *(const float4*)&V[(size_t)(k0 + sbr) * D3 + sbc];
    *(float4*)&Vs[8 + sbr][sbc] = *(const float4*)&V[(size_t)(k0 + 8 + sbr) * D3 + sbc];
    __syncthreads();
#pragma unroll
    for (int kk = 0; kk < 16; kk++) {
      float4 t = *(const float4*)&Ps[kk][tm];
      float av[4] = {t.x, t.y, t.z, t.w};
      float4 t0 = *(const float4*)&Vs[kk][tn];
      float4 t1 = *(const float4*)&Vs[kk][64 + tn];
      float bv[8] = {t0.x, t0.y, t0.z, t0.w, t1.x, t1.y, t1.z, t1.w};
#pragma unroll
      for (int i = 0; i < 4; i++)
#pragma unroll
        for (int j = 0; j < 8; j++)
          acc[i][j] = fmaf(av[i], bv[j], acc[i][j]);
    }
  }
#pragma unroll
  for (int i = 0; i < 4; i++) {
    const int row = bm + tm + i;
#pragma unroll
    for (int jb = 0; jb < 2; jb++) {
      float4 r = {acc[i][jb*4+0], acc[i][jb*4+1], acc[i][jb*4+2], acc[i][jb*4+3]};
      *(float4*)&o[(size_t)row * D_MODEL + h * HD + jb * 64 + tn] = r;
    }
  }
}

// ------------------------------------------------------------- final LN
__global__ __launch_bounds__(256)
void ln_kernel(const float* __restrict__ x, const float* __restrict__ g,
               const float* __restrict__ bb, float* __restrict__ y) {
  __shared__ float red[8];
  const int row = blockIdx.x;
  const float* xr = x + (size_t)row * D_MODEL;
  float v[6];
  float s = 0.f, sq = 0.f;
#pragma unroll
  for (int i = 0; i < 6; i++) {
    v[i] = xr[256 * i + threadIdx.x];
    s += v[i];
    sq += v[i] * v[i];
  }
#pragma unroll
  for (int off = 32; off >= 1; off >>= 1) {
    s += __shfl_down(s, off, 64);
    sq += __shfl_down(sq, off, 64);
  }
  const int lane = threadIdx.x & 63, w = threadIdx.x >> 6;
  if (lane == 0) { red[w] = s; red[4 + w] = sq; }
  __syncthreads();
  if (threadIdx.x == 0) {
    red[0] = red[0] + red[1] + red[2] + red[3];
    red[4] = red[4] + red[5] + red[6] + red[7];
  }
  __syncthreads();
  const float mu = red[0] * (1.f / D_MODEL);
  const float var = red[4] * (1.f / D_MODEL) - mu * mu;
  const float rs = rsqrtf(var + 1e-5f);
#pragma unroll
  for (int i = 0; i < 6; i++) {
    int c = 256 * i + threadIdx.x;
    y[(size_t)row * D_MODEL + c] = (v[i] - mu) * rs * g[c] + bb[c];
  }
}

// ------------------------------------------------------------- launcher
extern "C" void kernel_launch(void* const* d_in, const int* in_sizes, int n_in,
                              void* d_out, int out_size, void* d_ws, size_t ws_size,
                              hipStream_t stream) {
  (void)in_sizes; (void)n_in; (void)out_size; (void)ws_size;
  const int*   idx     = (const int*)d_in[0];
  const float* tok_emb = (const float*)d_in[2];
  const float* pos_emb = (const float*)d_in[3];
  const float* Wqkv    = (const float*)d_in[4];
  const float* bqkv    = (const float*)d_in[5];
  const float* Wo      = (const float*)d_in[6];
  const float* bo      = (const float*)d_in[7];
  const float* W1      = (const float*)d_in[8];
  const float* b1      = (const float*)d_in[9];
  const float* W2      = (const float*)d_in[10];
  const float* b2      = (const float*)d_in[11];
  const float* ln_g    = (const float*)d_in[12];
  const float* ln_b    = (const float*)d_in[13];
  const float* Wout    = (const float*)d_in[14];
  const float* bout    = (const float*)d_in[15];
  float* out = (float*)d_out;

  char* ws = (char*)d_ws;
  float* x      = (float*)(ws);                 //  6.29 MB
  float* qkv    = (float*)(ws + 6291456);       // 18.87 MB
  float* o      = (float*)(ws + 25165824);      //  6.29 MB
  float* stats  = (float*)(ws + 31457280);      //  0.10 MB
  float* pstats = (float*)(ws + 31555584);      //  0.79 MB
  float* U      = (float*)(ws + 32342016);      // 50.33 MB union {scores|h1|xn}
  float* scores = U;
  float* h1     = U;
  float* xn     = U;

  embed_kernel<<<6144, 256, 0, stream>>>(idx, tok_emb, pos_emb, x);

  for (int l = 0; l < NL; l++) {
    const float* wqkv = Wqkv + (size_t)l * D_MODEL * D3;
    const float* bq   = bqkv + (size_t)l * D3;
    const float* wo   = Wo   + (size_t)l * D_MODEL * D_MODEL;
    const float* bo_  = bo   + (size_t)l * D_MODEL;
    const float* w1   = W1   + (size_t)l * D_MODEL * D4;
    const float* b1_  = b1   + (size_t)l * D4;
    const float* w2   = W2   + (size_t)l * D4 * D_MODEL;
    const float* b2_  = b2   + (size_t)l * D_MODEL;

    gemm_kernel<2, false, false><<<dim3(36, 8), 256, 0, stream>>>(
        x, wqkv, bq, nullptr, qkv, SEQ, D3, D_MODEL);
    scores_kernel<<<dim3(8, 8, NH), 256, 0, stream>>>(qkv, scores);
    colstatA_kernel<<<384, 256, 0, stream>>>(scores, pstats);
    colstatB_kernel<<<48, 256, 0, stream>>>(pstats, stats);
    av_kernel<<<dim3(1, 16, NH), 256, 0, stream>>>(qkv, scores, stats, o);
    gemm_kernel<1, false, true><<<dim3(12, 16), 256, 0, stream>>>(
        o, wo, bo_, x, x, SEQ, D_MODEL, D_MODEL);
    gemm_kernel<2, true, false><<<dim3(48, 8), 256, 0, stream>>>(
        x, w1, b1_, nullptr, h1, SEQ, D4, D_MODEL);
    gemm_kernel<1, false, true><<<dim3(12, 16), 256, 0, stream>>>(
        h1, w2, b2_, x, x, SEQ, D_MODEL, D4);
  }

  ln_kernel<<<SEQ, 256, 0, stream>>>(x, ln_g, ln_b, xn);
  gemm_kernel<1, false, false><<<dim3(12, 16), 256, 0, stream>>>(
      xn, Wout, bout, nullptr, out, SEQ, D_MODEL, D_MODEL);
}

// Round 3
// 5719.528 us; speedup vs baseline: 3.2460x; 3.2460x over previous
//
#include <hip/hip_runtime.h>
#include <stdint.h>
#include <math.h>

#define D_MODEL 1536
#define NH 12
#define HD 128
#define NL 12
#define SEQ 1024
#define D3 4608
#define D4 6144
#define SCALE 0.025515518153991442f  // 1/sqrt(1536)

typedef __attribute__((ext_vector_type(8))) short short8;
typedef __attribute__((ext_vector_type(4))) float floatx4;

__device__ __forceinline__ short f2bf(float f) {
  union { float f; uint32_t u; } v; v.f = f;
  return (short)((v.u + 0x7FFFu + ((v.u >> 16) & 1u)) >> 16);  // RNE
}
// f32 = bf16(hi) + bf16(lo) with residual ~2^-17 relative
__device__ __forceinline__ void split2(float f, short &hi, short &lo) {
  union { float f; uint32_t u; } v; v.f = f;
  uint32_t hu = v.u & 0xFFFF0000u;
  hi = (short)(hu >> 16);
  union { uint32_t u; float f; } h; h.u = hu;
  lo = f2bf(f - h.f);
}

// ------------------------------------------------------------- embed
__global__ __launch_bounds__(256)
void embed_kernel(const int* __restrict__ idx, const float* __restrict__ tok,
                  const float* __restrict__ pos, float* __restrict__ x) {
  int i = blockIdx.x * 256 + threadIdx.x;
  int s = i / D_MODEL;
  int d = i - s * D_MODEL;
  x[i] = tok[(size_t)idx[s] * D_MODEL + d] + pos[d];  // pos row 0 quirk
}

// ------------------------------------------------------------- hi/lo MFMA GEMM
// C = A[M,K] @ B[K,N]; 3-pass (AhBh+AhBl+AlBh). BM x 128 tile, BK=32, 4 waves.
// SPLITK>1: blockIdx.z = K-chunk, raw partial to C + z*M*N (no bias/res/relu).
template<int BM, bool RELU, bool RES, int SPLITK>
__global__ __launch_bounds__(256)
void mgemm_kernel(const float* __restrict__ A, const float* __restrict__ B,
                  const float* __restrict__ bias, const float* __restrict__ res,
                  float* __restrict__ C, int M, int N, int K) {
  constexpr int MI = BM / 32;          // a-frags per wave
  constexpr int AE = BM / 8;           // A floats per thread per k-step
  constexpr int TPR = 32 / AE;         // threads per A row
  __shared__ short Ah[BM][40], Al[BM][40];
  __shared__ short Bh[128][40], Bl[128][40];
  const int tid = threadIdx.x;
  const int lane = tid & 63, wave = tid >> 6;
  const int bm = blockIdx.y * BM, bn = blockIdx.x << 7;
  const int wm = (wave >> 1) * (BM / 2), wn = (wave & 1) << 6;
  const int fr = lane & 15, fk = (lane >> 4) << 3;
  const int Kc = K / SPLITK;
  const int kbase = (SPLITK > 1) ? blockIdx.z * Kc : 0;

  floatx4 acc[MI][4];
#pragma unroll
  for (int i = 0; i < MI; i++)
#pragma unroll
    for (int j = 0; j < 4; j++) acc[i][j] = (floatx4){0.f, 0.f, 0.f, 0.f};

  const int ar = tid / TPR;
  const int ac = (tid % TPR) * AE;
  const int bc = tid & 127;
  const int bkq = (tid >> 7) << 4;

  for (int k0 = 0; k0 < Kc; k0 += 32) {
    __syncthreads();
    {  // A: row-major contiguous
      const float* Ap = A + (size_t)(bm + ar) * K + kbase + k0 + ac;
#pragma unroll
      for (int e = 0; e < AE / 8; e++) {
        float4 v0 = *(const float4*)(Ap + 8 * e);
        float4 v1 = *(const float4*)(Ap + 8 * e + 4);
        float t[8] = {v0.x, v0.y, v0.z, v0.w, v1.x, v1.y, v1.z, v1.w};
        short8 sh, sl;
#pragma unroll
        for (int j = 0; j < 8; j++) { short h, l; split2(t[j], h, l); sh[j] = h; sl[j] = l; }
        *(short8*)&Ah[ar][ac + 8 * e] = sh;
        *(short8*)&Al[ar][ac + 8 * e] = sl;
      }
    }
    {  // B: strided gather, store transposed [col][k]
      const float* Bp = B + (size_t)(kbase + k0 + bkq) * N + bn + bc;
#pragma unroll
      for (int e = 0; e < 2; e++) {
        short8 sh, sl;
#pragma unroll
        for (int j = 0; j < 8; j++) {
          short h, l; split2(Bp[(size_t)(8 * e + j) * N], h, l); sh[j] = h; sl[j] = l;
        }
        *(short8*)&Bh[bc][bkq + 8 * e] = sh;
        *(short8*)&Bl[bc][bkq + 8 * e] = sl;
      }
    }
    __syncthreads();
    short8 ah[MI], al[MI], bh[4], bl[4];
#pragma unroll
    for (int i = 0; i < MI; i++) {
      ah[i] = *(const short8*)&Ah[wm + (i << 4) + fr][fk];
      al[i] = *(const short8*)&Al[wm + (i << 4) + fr][fk];
    }
#pragma unroll
    for (int j = 0; j < 4; j++) {
      bh[j] = *(const short8*)&Bh[wn + (j << 4) + fr][fk];
      bl[j] = *(const short8*)&Bl[wn + (j << 4) + fr][fk];
    }
#pragma unroll
    for (int i = 0; i < MI; i++)
#pragma unroll
      for (int j = 0; j < 4; j++) {
        acc[i][j] = __builtin_amdgcn_mfma_f32_16x16x32_bf16(ah[i], bh[j], acc[i][j], 0, 0, 0);
        acc[i][j] = __builtin_amdgcn_mfma_f32_16x16x32_bf16(ah[i], bl[j], acc[i][j], 0, 0, 0);
        acc[i][j] = __builtin_amdgcn_mfma_f32_16x16x32_bf16(al[i], bh[j], acc[i][j], 0, 0, 0);
      }
  }

  const int cr = (lane >> 4) << 2, cc = lane & 15;
  if constexpr (SPLITK > 1) {
    float* Cp = C + (size_t)blockIdx.z * M * N;
#pragma unroll
    for (int j = 0; j < 4; j++) {
      const int col = bn + wn + (j << 4) + cc;
#pragma unroll
      for (int i = 0; i < MI; i++) {
        const int row0 = bm + wm + (i << 4) + cr;
#pragma unroll
        for (int r = 0; r < 4; r++)
          Cp[(size_t)(row0 + r) * N + col] = acc[i][j][r];
      }
    }
  } else {
#pragma unroll
    for (int j = 0; j < 4; j++) {
      const int col = bn + wn + (j << 4) + cc;
      const float bv = bias[col];
#pragma unroll
      for (int i = 0; i < MI; i++) {
        const int row0 = bm + wm + (i << 4) + cr;
#pragma unroll
        for (int r = 0; r < 4; r++) {
          float v = acc[i][j][r] + bv;
          if constexpr (RES) v += res[(size_t)(row0 + r) * N + col];
          if constexpr (RELU) v = fmaxf(v, 0.f);
          C[(size_t)(row0 + r) * N + col] = v;
        }
      }
    }
  }
}

// ------------------------------------------------------------- combine (split-K)
template<bool HASB, bool RES, bool RELU>
__global__ __launch_bounds__(256)
void combine_kernel(const float* __restrict__ p0, const float* __restrict__ p1,
                    const float* __restrict__ bias, const float* __restrict__ res,
                    float* __restrict__ C, int N) {
  const int i = (blockIdx.x * 256 + threadIdx.x) << 2;
  float4 a = *(const float4*)&p0[i];
  float4 b = *(const float4*)&p1[i];
  float4 r = {a.x + b.x, a.y + b.y, a.z + b.z, a.w + b.w};
  if constexpr (HASB) {
    const int col = i % N;
    float4 bv = *(const float4*)&bias[col];
    r.x += bv.x; r.y += bv.y; r.z += bv.z; r.w += bv.w;
  }
  if constexpr (RES) {
    float4 rv = *(const float4*)&res[i];
    r.x += rv.x; r.y += rv.y; r.z += rv.z; r.w += rv.w;
  }
  if constexpr (RELU) {
    r.x = fmaxf(r.x, 0.f); r.y = fmaxf(r.y, 0.f);
    r.z = fmaxf(r.z, 0.f); r.w = fmaxf(r.w, 0.f);
  }
  *(float4*)&C[i] = r;
}

// ------------------------------------------------------------- scores (4-pass MFMA)
// scores[h][i][j] = (j<=i) ? SCALE * q_i . k_j : -1e30
__global__ __launch_bounds__(256)
void scores_kernel(const float* __restrict__ qkv, float* __restrict__ scores) {
  __shared__ short Qh[128][40], Ql[128][40], Kh[128][40], Kl[128][40];
  const int tid = threadIdx.x;
  const int lane = tid & 63, wave = tid >> 6;
  const int h = blockIdx.z;
  const int bi = blockIdx.y << 7, bj = blockIdx.x << 7;
  const int wm = (wave >> 1) << 6, wn = (wave & 1) << 6;
  const int fr = lane & 15, fk = (lane >> 4) << 3;
  const float* Q = qkv + h * HD;
  const float* Kp = qkv + D_MODEL + h * HD;

  floatx4 acc[4][4];
#pragma unroll
  for (int i = 0; i < 4; i++)
#pragma unroll
    for (int j = 0; j < 4; j++) acc[i][j] = (floatx4){0.f, 0.f, 0.f, 0.f};

  const int ar = tid >> 1;
  const int ac = (tid & 1) << 4;

  for (int k0 = 0; k0 < HD; k0 += 32) {
    __syncthreads();
    {
      const float* Qp = Q + (size_t)(bi + ar) * D3 + k0 + ac;
#pragma unroll
      for (int e = 0; e < 2; e++) {
        float4 v0 = *(const float4*)(Qp + 8 * e);
        float4 v1 = *(const float4*)(Qp + 8 * e + 4);
        float t[8] = {v0.x, v0.y, v0.z, v0.w, v1.x, v1.y, v1.z, v1.w};
        short8 sh, sl;
#pragma unroll
        for (int j = 0; j < 8; j++) { short h2, l; split2(t[j], h2, l); sh[j] = h2; sl[j] = l; }
        *(short8*)&Qh[ar][ac + 8 * e] = sh;
        *(short8*)&Ql[ar][ac + 8 * e] = sl;
      }
      const float* Kpp = Kp + (size_t)(bj + ar) * D3 + k0 + ac;
#pragma unroll
      for (int e = 0; e < 2; e++) {
        float4 v0 = *(const float4*)(Kpp + 8 * e);
        float4 v1 = *(const float4*)(Kpp + 8 * e + 4);
        float t[8] = {v0.x, v0.y, v0.z, v0.w, v1.x, v1.y, v1.z, v1.w};
        short8 sh, sl;
#pragma unroll
        for (int j = 0; j < 8; j++) { short h2, l; split2(t[j], h2, l); sh[j] = h2; sl[j] = l; }
        *(short8*)&Kh[ar][ac + 8 * e] = sh;
        *(short8*)&Kl[ar][ac + 8 * e] = sl;
      }
    }
    __syncthreads();
    short8 qh[4], ql[4], kh[4], kl[4];
#pragma unroll
    for (int i = 0; i < 4; i++) {
      qh[i] = *(const short8*)&Qh[wm + (i << 4) + fr][fk];
      ql[i] = *(const short8*)&Ql[wm + (i << 4) + fr][fk];
      kh[i] = *(const short8*)&Kh[wn + (i << 4) + fr][fk];
      kl[i] = *(const short8*)&Kl[wn + (i << 4) + fr][fk];
    }
#pragma unroll
    for (int i = 0; i < 4; i++)
#pragma unroll
      for (int j = 0; j < 4; j++) {
        acc[i][j] = __builtin_amdgcn_mfma_f32_16x16x32_bf16(qh[i], kh[j], acc[i][j], 0, 0, 0);
        acc[i][j] = __builtin_amdgcn_mfma_f32_16x16x32_bf16(qh[i], kl[j], acc[i][j], 0, 0, 0);
        acc[i][j] = __builtin_amdgcn_mfma_f32_16x16x32_bf16(ql[i], kh[j], acc[i][j], 0, 0, 0);
        acc[i][j] = __builtin_amdgcn_mfma_f32_16x16x32_bf16(ql[i], kl[j], acc[i][j], 0, 0, 0);
      }
  }

  const int cr = (lane >> 4) << 2, cc = lane & 15;
  float* S = scores + (size_t)h * SEQ * SEQ;
#pragma unroll
  for (int j = 0; j < 4; j++) {
    const int col = bj + wn + (j << 4) + cc;
#pragma unroll
    for (int i = 0; i < 4; i++) {
      const int row0 = bi + wm + (i << 4) + cr;
#pragma unroll
      for (int r = 0; r < 4; r++) {
        float v = acc[i][j][r] * SCALE;
        S[(size_t)(row0 + r) * SEQ + col] = (col <= row0 + r) ? v : -1e30f;
      }
    }
  }
}

// ------------------------------------------------------------- column stats
__global__ __launch_bounds__(256)
void colstatA_kernel(const float* __restrict__ scores, float* __restrict__ pstats) {
  const int b = blockIdx.x;
  const int h = b >> 5;
  const int cc = (b >> 3) & 3;
  const int qc = b & 7;
  const int c = (cc << 8) + threadIdx.x;
  const int q0 = qc << 7;
  const float* Sc = scores + (size_t)h * SEQ * SEQ + c;
  float m = -1e30f, z = 0.f;
  for (int q = q0; q < q0 + 128; q++) {
    if (q >= c) {
      float sv = Sc[(size_t)q * SEQ];
      float mn = fmaxf(m, sv);
      z = z * expf(m - mn) + expf(sv - mn);
      m = mn;
    }
  }
  pstats[(size_t)((h * 8 + qc) * 2 + 0) * 1024 + c] = m;
  pstats[(size_t)((h * 8 + qc) * 2 + 1) * 1024 + c] = z;
}

__global__ __launch_bounds__(256)
void colstatB_kernel(const float* __restrict__ pstats, float* __restrict__ stats) {
  const int i = blockIdx.x * 256 + threadIdx.x;
  const int h = i >> 10, c = i & 1023;
  float m = -1e30f;
#pragma unroll
  for (int qc = 0; qc < 8; qc++)
    m = fmaxf(m, pstats[(size_t)((h * 8 + qc) * 2 + 0) * 1024 + c]);
  float z = 0.f;
#pragma unroll
  for (int qc = 0; qc < 8; qc++) {
    float pm = pstats[(size_t)((h * 8 + qc) * 2 + 0) * 1024 + c];
    float pz = pstats[(size_t)((h * 8 + qc) * 2 + 1) * 1024 + c];
    z += pz * expf(pm - m);
  }
  stats[h * 2048 + c] = m;
  stats[h * 2048 + 1024 + c] = 1.f / z;
}

// ------------------------------------------------------------- attn @ V (3-pass, splitK=2)
__global__ __launch_bounds__(256)
void av_kernel(const float* __restrict__ qkv, const float* __restrict__ scores,
               const float* __restrict__ stats, float* __restrict__ part) {
  __shared__ short Ph[64][40], Pl[64][40], Vh[128][40], Vl[128][40];
  const int tid = threadIdx.x;
  const int lane = tid & 63, wave = tid >> 6;
  const int h = blockIdx.z >> 1, z = blockIdx.z & 1;
  const int bm = blockIdx.y << 6;
  const int wm = (wave >> 1) << 5, wn = (wave & 1) << 6;
  const int fr = lane & 15, fk = (lane >> 4) << 3;
  const float* S = scores + (size_t)h * SEQ * SEQ;
  const float* Mh = stats + h * 2048;
  const float* Rh = Mh + 1024;
  const float* V = qkv + 2 * D_MODEL + h * HD;

  floatx4 acc[2][4];
#pragma unroll
  for (int i = 0; i < 2; i++)
#pragma unroll
    for (int j = 0; j < 4; j++) acc[i][j] = (floatx4){0.f, 0.f, 0.f, 0.f};

  const int ar = tid >> 2;
  const int ac = (tid & 3) << 3;
  const int bc = tid & 127;
  const int bkq = (tid >> 7) << 4;

  for (int k0 = z * 512; k0 < z * 512 + 512; k0 += 32) {
    __syncthreads();
    {  // P = exp(s - M[k]) * rZ[k], split hi/lo
      const float* Sp = S + (size_t)(bm + ar) * SEQ + k0 + ac;
      float4 v0 = *(const float4*)(Sp);
      float4 v1 = *(const float4*)(Sp + 4);
      float t[8] = {v0.x, v0.y, v0.z, v0.w, v1.x, v1.y, v1.z, v1.w};
      short8 sh, sl;
#pragma unroll
      for (int j = 0; j < 8; j++) {
        int kk = k0 + ac + j;
        float p = expf(t[j] - Mh[kk]) * Rh[kk];
        short h2, l; split2(p, h2, l); sh[j] = h2; sl[j] = l;
      }
      *(short8*)&Ph[ar][ac] = sh;
      *(short8*)&Pl[ar][ac] = sl;
    }
    {  // V: strided gather -> [d][k]
      const float* Vp = V + (size_t)(k0 + bkq) * D3 + bc;
#pragma unroll
      for (int e = 0; e < 2; e++) {
        short8 sh, sl;
#pragma unroll
        for (int j = 0; j < 8; j++) {
          short h2, l; split2(Vp[(size_t)(8 * e + j) * D3], h2, l); sh[j] = h2; sl[j] = l;
        }
        *(short8*)&Vh[bc][bkq + 8 * e] = sh;
        *(short8*)&Vl[bc][bkq + 8 * e] = sl;
      }
    }
    __syncthreads();
    short8 ph[2], pl[2], vh[4], vl[4];
#pragma unroll
    for (int i = 0; i < 2; i++) {
      ph[i] = *(const short8*)&Ph[wm + (i << 4) + fr][fk];
      pl[i] = *(const short8*)&Pl[wm + (i << 4) + fr][fk];
    }
#pragma unroll
    for (int j = 0; j < 4; j++) {
      vh[j] = *(const short8*)&Vh[wn + (j << 4) + fr][fk];
      vl[j] = *(const short8*)&Vl[wn + (j << 4) + fr][fk];
    }
#pragma unroll
    for (int i = 0; i < 2; i++)
#pragma unroll
      for (int j = 0; j < 4; j++) {
        acc[i][j] = __builtin_amdgcn_mfma_f32_16x16x32_bf16(ph[i], vh[j], acc[i][j], 0, 0, 0);
        acc[i][j] = __builtin_amdgcn_mfma_f32_16x16x32_bf16(ph[i], vl[j], acc[i][j], 0, 0, 0);
        acc[i][j] = __builtin_amdgcn_mfma_f32_16x16x32_bf16(pl[i], vh[j], acc[i][j], 0, 0, 0);
      }
  }

  const int cr = (lane >> 4) << 2, cc = lane & 15;
  float* Cp = part + (size_t)z * SEQ * D_MODEL;
#pragma unroll
  for (int j = 0; j < 4; j++) {
    const int col = h * HD + wn + (j << 4) + cc;
#pragma unroll
    for (int i = 0; i < 2; i++) {
      const int row0 = bm + wm + (i << 4) + cr;
#pragma unroll
      for (int r = 0; r < 4; r++)
        Cp[(size_t)(row0 + r) * D_MODEL + col] = acc[i][j][r];
    }
  }
}

// ------------------------------------------------------------- final LN
__global__ __launch_bounds__(256)
void ln_kernel(const float* __restrict__ x, const float* __restrict__ g,
               const float* __restrict__ bb, float* __restrict__ y) {
  __shared__ float red[8];
  const int row = blockIdx.x;
  const float* xr = x + (size_t)row * D_MODEL;
  float v[6];
  float s = 0.f, sq = 0.f;
#pragma unroll
  for (int i = 0; i < 6; i++) {
    v[i] = xr[256 * i + threadIdx.x];
    s += v[i];
    sq += v[i] * v[i];
  }
#pragma unroll
  for (int off = 32; off >= 1; off >>= 1) {
    s += __shfl_down(s, off, 64);
    sq += __shfl_down(sq, off, 64);
  }
  const int lane = threadIdx.x & 63, w = threadIdx.x >> 6;
  if (lane == 0) { red[w] = s; red[4 + w] = sq; }
  __syncthreads();
  if (threadIdx.x == 0) {
    red[0] = red[0] + red[1] + red[2] + red[3];
    red[4] = red[4] + red[5] + red[6] + red[7];
  }
  __syncthreads();
  const float mu = red[0] * (1.f / D_MODEL);
  const float var = red[4] * (1.f / D_MODEL) - mu * mu;
  const float rs = rsqrtf(var + 1e-5f);
#pragma unroll
  for (int i = 0; i < 6; i++) {
    int c = 256 * i + threadIdx.x;
    y[(size_t)row * D_MODEL + c] = (v[i] - mu) * rs * g[c] + bb[c];
  }
}

// ------------------------------------------------------------- launcher
extern "C" void kernel_launch(void* const* d_in, const int* in_sizes, int n_in,
                              void* d_out, int out_size, void* d_ws, size_t ws_size,
                              hipStream_t stream) {
  (void)in_sizes; (void)n_in; (void)out_size; (void)ws_size;
  const int*   idx     = (const int*)d_in[0];
  const float* tok_emb = (const float*)d_in[2];
  const float* pos_emb = (const float*)d_in[3];
  const float* Wqkv    = (const float*)d_in[4];
  const float* bqkv    = (const float*)d_in[5];
  const float* Wo      = (const float*)d_in[6];
  const float* bo      = (const float*)d_in[7];
  const float* W1      = (const float*)d_in[8];
  const float* b1      = (const float*)d_in[9];
  const float* W2      = (const float*)d_in[10];
  const float* b2      = (const float*)d_in[11];
  const float* ln_g    = (const float*)d_in[12];
  const float* ln_b    = (const float*)d_in[13];
  const float* Wout    = (const float*)d_in[14];
  const float* bout    = (const float*)d_in[15];
  float* out = (float*)d_out;

  char* ws = (char*)d_ws;
  float* x      = (float*)(ws);                 //  6.29 MB
  float* qkv    = (float*)(ws + 6291456);       // 18.87 MB
  float* o      = (float*)(ws + 25165824);      //  6.29 MB
  float* stats  = (float*)(ws + 31457280);      //  0.10 MB
  float* pstats = (float*)(ws + 31555584);      //  0.79 MB
  float* part   = (float*)(ws + 32342016);      // 12.58 MB (2 x M*N partials)
  float* U      = (float*)(ws + 44924928);      // 50.33 MB union {scores|h1|xn}
  float* scores = U;
  float* h1     = U;
  float* xn     = U;
  const int PN = SEQ * D_MODEL;

  embed_kernel<<<6144, 256, 0, stream>>>(idx, tok_emb, pos_emb, x);

  for (int l = 0; l < NL; l++) {
    const float* wqkv = Wqkv + (size_t)l * D_MODEL * D3;
    const float* bq   = bqkv + (size_t)l * D3;
    const float* wo   = Wo   + (size_t)l * D_MODEL * D_MODEL;
    const float* bo_  = bo   + (size_t)l * D_MODEL;
    const float* w1   = W1   + (size_t)l * D_MODEL * D4;
    const float* b1_  = b1   + (size_t)l * D4;
    const float* w2   = W2   + (size_t)l * D4 * D_MODEL;
    const float* b2_  = b2   + (size_t)l * D_MODEL;

    mgemm_kernel<128, false, false, 1><<<dim3(36, 8), 256, 0, stream>>>(
        x, wqkv, bq, nullptr, qkv, SEQ, D3, D_MODEL);
    scores_kernel<<<dim3(8, 8, NH), 256, 0, stream>>>(qkv, scores);
    colstatA_kernel<<<384, 256, 0, stream>>>(scores, pstats);
    colstatB_kernel<<<48, 256, 0, stream>>>(pstats, stats);
    av_kernel<<<dim3(1, 16, 24), 256, 0, stream>>>(qkv, scores, stats, part);
    combine_kernel<false, false, false><<<1536, 256, 0, stream>>>(
        part, part + PN, nullptr, nullptr, o, D_MODEL);
    mgemm_kernel<64, false, false, 2><<<dim3(12, 16, 2), 256, 0, stream>>>(
        o, wo, nullptr, nullptr, part, SEQ, D_MODEL, D_MODEL);
    combine_kernel<true, true, false><<<1536, 256, 0, stream>>>(
        part, part + PN, bo_, x, x, D_MODEL);
    mgemm_kernel<128, true, false, 1><<<dim3(48, 8), 256, 0, stream>>>(
        x, w1, b1_, nullptr, h1, SEQ, D4, D_MODEL);
    mgemm_kernel<64, false, false, 2><<<dim3(12, 16, 2), 256, 0, stream>>>(
        h1, w2, nullptr, nullptr, part, SEQ, D_MODEL, D4);
    combine_kernel<true, true, false><<<1536, 256, 0, stream>>>(
        part, part + PN, b2_, x, x, D_MODEL);
  }

  ln_kernel<<<SEQ, 256, 0, stream>>>(x, ln_g, ln_b, xn);
  mgemm_kernel<64, false, false, 2><<<dim3(12, 16, 2), 256, 0, stream>>>(
      xn, Wout, nullptr, nullptr, part, SEQ, D_MODEL, D_MODEL);
  combine_kernel<true, false, false><<<1536, 256, 0, stream>>>(
      part, part + PN, bout, nullptr, out, D_MODEL);
}

// Round 4
// 5639.831 us; speedup vs baseline: 3.2919x; 1.0141x over previous
//
#include <hip/hip_runtime.h>
#include <stdint.h>
#include <math.h>

#define D_MODEL 1536
#define NH 12
#define HD 128
#define NL 12
#define SEQ 1024
#define D3 4608
#define D4 6144
#define SCALE 0.025515518153991442f  // 1/sqrt(1536)

typedef __attribute__((ext_vector_type(8))) short short8;
typedef __attribute__((ext_vector_type(4))) float floatx4;

// ---- cheap hi/lo split: hi = bit-trunc bf16, lo = bf16(f - hi) (exact sub)
__device__ __forceinline__ uint32_t packhi(float a, float b) {
  return (__float_as_uint(a) >> 16) | (__float_as_uint(b) & 0xFFFF0000u);
}
__device__ __forceinline__ float truncf32(float a) {
  return __uint_as_float(__float_as_uint(a) & 0xFFFF0000u);
}
__device__ __forceinline__ void split8v(float4 v0, float4 v1, uint4 &hi, uint4 &lo) {
  hi.x = packhi(v0.x, v0.y); hi.y = packhi(v0.z, v0.w);
  hi.z = packhi(v1.x, v1.y); hi.w = packhi(v1.z, v1.w);
  lo.x = packhi(v0.x - truncf32(v0.x), v0.y - truncf32(v0.y));
  lo.y = packhi(v0.z - truncf32(v0.z), v0.w - truncf32(v0.w));
  lo.z = packhi(v1.x - truncf32(v1.x), v1.y - truncf32(v1.y));
  lo.w = packhi(v1.z - truncf32(v1.z), v1.w - truncf32(v1.w));
}

// ---- bijective XCD-chunked block remap (m204); safe: bijection only
__device__ __forceinline__ int xcd_chunk_id(int nwg) {
  int orig = blockIdx.x;
  int xcd = orig & 7, pos = orig >> 3;
  int q = nwg >> 3, r = nwg & 7;
  return (xcd < r ? xcd * (q + 1) : r * (q + 1) + (xcd - r) * q) + pos;
}

// ------------------------------------------------------------- embed
__global__ __launch_bounds__(256)
void embed_kernel(const int* __restrict__ idx, const float* __restrict__ tok,
                  const float* __restrict__ pos, float* __restrict__ x) {
  int i = blockIdx.x * 256 + threadIdx.x;
  int s = i / D_MODEL;
  int d = i - s * D_MODEL;
  x[i] = tok[(size_t)idx[s] * D_MODEL + d] + pos[d];  // pos row 0 quirk
}

// ------------------------------------------------------------- hi/lo MFMA GEMM
// C = A[M,K] @ B[K,N]; 3-pass (AhBh+AhBl+AlBh). BM x 128 tile, BK=32, 4 waves.
// 1D grid, logical id = z*(NC*NR) + ct*NR + rt  (row-tiles contiguous -> share B panel)
template<int BM, bool RELU, bool RES, int SPLITK>
__global__ __launch_bounds__(256)
void mgemm_kernel(const float* __restrict__ A, const float* __restrict__ B,
                  const float* __restrict__ bias, const float* __restrict__ res,
                  float* __restrict__ C, int M, int N, int K, int NC, int NR) {
  constexpr int MI = BM / 32;          // a-frags per wave
  constexpr int AE = BM / 8;           // A floats per thread per k-step
  constexpr int TPR = 32 / AE;         // threads per A row
  __shared__ short Ah[BM][40], Al[BM][40];
  __shared__ short Bh[128][40], Bl[128][40];
  const int tid = threadIdx.x;
  const int lane = tid & 63, wave = tid >> 6;

  const int lid = xcd_chunk_id(NC * NR * SPLITK);
  const int z   = lid / (NC * NR);
  const int rem = lid - z * (NC * NR);
  const int ct  = rem / NR;
  const int rt  = rem - ct * NR;
  const int bm = rt * BM, bn = ct << 7;

  const int wm = (wave >> 1) * (BM / 2), wn = (wave & 1) << 6;
  const int fr = lane & 15, fk = (lane >> 4) << 3;
  const int Kc = K / SPLITK;
  const int kbase = (SPLITK > 1) ? z * Kc : 0;

  floatx4 acc[MI][4];
#pragma unroll
  for (int i = 0; i < MI; i++)
#pragma unroll
    for (int j = 0; j < 4; j++) acc[i][j] = (floatx4){0.f, 0.f, 0.f, 0.f};

  const int ar = tid / TPR;
  const int ac = (tid % TPR) * AE;
  const int bc = tid & 127;
  const int bkq = (tid >> 7) << 4;

  for (int k0 = 0; k0 < Kc; k0 += 32) {
    __syncthreads();
    {  // A: row-major contiguous
      const float* Ap = A + (size_t)(bm + ar) * K + kbase + k0 + ac;
#pragma unroll
      for (int e = 0; e < AE / 8; e++) {
        float4 v0 = *(const float4*)(Ap + 8 * e);
        float4 v1 = *(const float4*)(Ap + 8 * e + 4);
        uint4 hi, lo; split8v(v0, v1, hi, lo);
        *(uint4*)&Ah[ar][ac + 8 * e] = hi;
        *(uint4*)&Al[ar][ac + 8 * e] = lo;
      }
    }
    {  // B: strided gather, store transposed [col][k]
      const float* Bp = B + (size_t)(kbase + k0 + bkq) * N + bn + bc;
#pragma unroll
      for (int e = 0; e < 2; e++) {
        float4 u0, u1;
        u0.x = Bp[(size_t)(8 * e + 0) * N]; u0.y = Bp[(size_t)(8 * e + 1) * N];
        u0.z = Bp[(size_t)(8 * e + 2) * N]; u0.w = Bp[(size_t)(8 * e + 3) * N];
        u1.x = Bp[(size_t)(8 * e + 4) * N]; u1.y = Bp[(size_t)(8 * e + 5) * N];
        u1.z = Bp[(size_t)(8 * e + 6) * N]; u1.w = Bp[(size_t)(8 * e + 7) * N];
        uint4 hi, lo; split8v(u0, u1, hi, lo);
        *(uint4*)&Bh[bc][bkq + 8 * e] = hi;
        *(uint4*)&Bl[bc][bkq + 8 * e] = lo;
      }
    }
    __syncthreads();
    short8 ah[MI], al[MI], bh[4], bl[4];
#pragma unroll
    for (int i = 0; i < MI; i++) {
      ah[i] = *(const short8*)&Ah[wm + (i << 4) + fr][fk];
      al[i] = *(const short8*)&Al[wm + (i << 4) + fr][fk];
    }
#pragma unroll
    for (int j = 0; j < 4; j++) {
      bh[j] = *(const short8*)&Bh[wn + (j << 4) + fr][fk];
      bl[j] = *(const short8*)&Bl[wn + (j << 4) + fr][fk];
    }
#pragma unroll
    for (int i = 0; i < MI; i++)
#pragma unroll
      for (int j = 0; j < 4; j++) {
        acc[i][j] = __builtin_amdgcn_mfma_f32_16x16x32_bf16(ah[i], bh[j], acc[i][j], 0, 0, 0);
        acc[i][j] = __builtin_amdgcn_mfma_f32_16x16x32_bf16(ah[i], bl[j], acc[i][j], 0, 0, 0);
        acc[i][j] = __builtin_amdgcn_mfma_f32_16x16x32_bf16(al[i], bh[j], acc[i][j], 0, 0, 0);
      }
  }

  const int cr = (lane >> 4) << 2, cc = lane & 15;
  if constexpr (SPLITK > 1) {
    float* Cp = C + (size_t)z * M * N;
#pragma unroll
    for (int j = 0; j < 4; j++) {
      const int col = bn + wn + (j << 4) + cc;
#pragma unroll
      for (int i = 0; i < MI; i++) {
        const int row0 = bm + wm + (i << 4) + cr;
#pragma unroll
        for (int r = 0; r < 4; r++)
          Cp[(size_t)(row0 + r) * N + col] = acc[i][j][r];
      }
    }
  } else {
#pragma unroll
    for (int j = 0; j < 4; j++) {
      const int col = bn + wn + (j << 4) + cc;
      const float bv = bias[col];
#pragma unroll
      for (int i = 0; i < MI; i++) {
        const int row0 = bm + wm + (i << 4) + cr;
#pragma unroll
        for (int r = 0; r < 4; r++) {
          float v = acc[i][j][r] + bv;
          if constexpr (RES) v += res[(size_t)(row0 + r) * N + col];
          if constexpr (RELU) v = fmaxf(v, 0.f);
          C[(size_t)(row0 + r) * N + col] = v;
        }
      }
    }
  }
}

// ------------------------------------------------------------- combine (split-K)
template<bool HASB, bool RES, bool RELU>
__global__ __launch_bounds__(256)
void combine_kernel(const float* __restrict__ p0, const float* __restrict__ p1,
                    const float* __restrict__ bias, const float* __restrict__ res,
                    float* __restrict__ C, int N) {
  const int i = (blockIdx.x * 256 + threadIdx.x) << 2;
  float4 a = *(const float4*)&p0[i];
  float4 b = *(const float4*)&p1[i];
  float4 r = {a.x + b.x, a.y + b.y, a.z + b.z, a.w + b.w};
  if constexpr (HASB) {
    const int col = i % N;
    float4 bv = *(const float4*)&bias[col];
    r.x += bv.x; r.y += bv.y; r.z += bv.z; r.w += bv.w;
  }
  if constexpr (RES) {
    float4 rv = *(const float4*)&res[i];
    r.x += rv.x; r.y += rv.y; r.z += rv.z; r.w += rv.w;
  }
  if constexpr (RELU) {
    r.x = fmaxf(r.x, 0.f); r.y = fmaxf(r.y, 0.f);
    r.z = fmaxf(r.z, 0.f); r.w = fmaxf(r.w, 0.f);
  }
  *(float4*)&C[i] = r;
}

// ------------------------------------------------------------- scores (4-pass MFMA)
// scores[h][i][j] = (j<=i) ? SCALE * q_i . k_j : -1e30
__global__ __launch_bounds__(256)
void scores_kernel(const float* __restrict__ qkv, float* __restrict__ scores) {
  __shared__ short Qh[128][40], Ql[128][40], Kh[128][40], Kl[128][40];
  const int tid = threadIdx.x;
  const int lane = tid & 63, wave = tid >> 6;

  const int lid = xcd_chunk_id(NH * 64);        // h*64 + bjt*8 + bit
  const int h = lid >> 6;
  const int bj = ((lid >> 3) & 7) << 7;
  const int bi = (lid & 7) << 7;

  const int wm = (wave >> 1) << 6, wn = (wave & 1) << 6;
  const int fr = lane & 15, fk = (lane >> 4) << 3;
  const float* Q = qkv + h * HD;
  const float* Kp = qkv + D_MODEL + h * HD;

  floatx4 acc[4][4];
#pragma unroll
  for (int i = 0; i < 4; i++)
#pragma unroll
    for (int j = 0; j < 4; j++) acc[i][j] = (floatx4){0.f, 0.f, 0.f, 0.f};

  const int ar = tid >> 1;
  const int ac = (tid & 1) << 4;

  for (int k0 = 0; k0 < HD; k0 += 32) {
    __syncthreads();
    {
      const float* Qp = Q + (size_t)(bi + ar) * D3 + k0 + ac;
#pragma unroll
      for (int e = 0; e < 2; e++) {
        float4 v0 = *(const float4*)(Qp + 8 * e);
        float4 v1 = *(const float4*)(Qp + 8 * e + 4);
        uint4 hi, lo; split8v(v0, v1, hi, lo);
        *(uint4*)&Qh[ar][ac + 8 * e] = hi;
        *(uint4*)&Ql[ar][ac + 8 * e] = lo;
      }
      const float* Kpp = Kp + (size_t)(bj + ar) * D3 + k0 + ac;
#pragma unroll
      for (int e = 0; e < 2; e++) {
        float4 v0 = *(const float4*)(Kpp + 8 * e);
        float4 v1 = *(const float4*)(Kpp + 8 * e + 4);
        uint4 hi, lo; split8v(v0, v1, hi, lo);
        *(uint4*)&Kh[ar][ac + 8 * e] = hi;
        *(uint4*)&Kl[ar][ac + 8 * e] = lo;
      }
    }
    __syncthreads();
    short8 qh[4], ql[4], kh[4], kl[4];
#pragma unroll
    for (int i = 0; i < 4; i++) {
      qh[i] = *(const short8*)&Qh[wm + (i << 4) + fr][fk];
      ql[i] = *(const short8*)&Ql[wm + (i << 4) + fr][fk];
      kh[i] = *(const short8*)&Kh[wn + (i << 4) + fr][fk];
      kl[i] = *(const short8*)&Kl[wn + (i << 4) + fr][fk];
    }
#pragma unroll
    for (int i = 0; i < 4; i++)
#pragma unroll
      for (int j = 0; j < 4; j++) {
        acc[i][j] = __builtin_amdgcn_mfma_f32_16x16x32_bf16(qh[i], kh[j], acc[i][j], 0, 0, 0);
        acc[i][j] = __builtin_amdgcn_mfma_f32_16x16x32_bf16(qh[i], kl[j], acc[i][j], 0, 0, 0);
        acc[i][j] = __builtin_amdgcn_mfma_f32_16x16x32_bf16(ql[i], kh[j], acc[i][j], 0, 0, 0);
        acc[i][j] = __builtin_amdgcn_mfma_f32_16x16x32_bf16(ql[i], kl[j], acc[i][j], 0, 0, 0);
      }
  }

  const int cr = (lane >> 4) << 2, cc = lane & 15;
  float* S = scores + (size_t)h * SEQ * SEQ;
#pragma unroll
  for (int j = 0; j < 4; j++) {
    const int col = bj + wn + (j << 4) + cc;
#pragma unroll
    for (int i = 0; i < 4; i++) {
      const int row0 = bi + wm + (i << 4) + cr;
#pragma unroll
      for (int r = 0; r < 4; r++) {
        float v = acc[i][j][r] * SCALE;
        S[(size_t)(row0 + r) * SEQ + col] = (col <= row0 + r) ? v : -1e30f;
      }
    }
  }
}

// ------------------------------------------------------------- column stats
__global__ __launch_bounds__(256)
void colstatA_kernel(const float* __restrict__ scores, float* __restrict__ pstats) {
  const int b = blockIdx.x;
  const int h = b >> 5;
  const int cc = (b >> 3) & 3;
  const int qc = b & 7;
  const int c = (cc << 8) + threadIdx.x;
  const int q0 = qc << 7;
  const float* Sc = scores + (size_t)h * SEQ * SEQ + c;
  float m = -1e30f, z = 0.f;
  for (int q = q0; q < q0 + 128; q++) {
    if (q >= c) {
      float sv = Sc[(size_t)q * SEQ];
      float mn = fmaxf(m, sv);
      z = z * expf(m - mn) + expf(sv - mn);
      m = mn;
    }
  }
  pstats[(size_t)((h * 8 + qc) * 2 + 0) * 1024 + c] = m;
  pstats[(size_t)((h * 8 + qc) * 2 + 1) * 1024 + c] = z;
}

__global__ __launch_bounds__(256)
void colstatB_kernel(const float* __restrict__ pstats, float* __restrict__ stats) {
  const int i = blockIdx.x * 256 + threadIdx.x;
  const int h = i >> 10, c = i & 1023;
  float m = -1e30f;
#pragma unroll
  for (int qc = 0; qc < 8; qc++)
    m = fmaxf(m, pstats[(size_t)((h * 8 + qc) * 2 + 0) * 1024 + c]);
  float z = 0.f;
#pragma unroll
  for (int qc = 0; qc < 8; qc++) {
    float pm = pstats[(size_t)((h * 8 + qc) * 2 + 0) * 1024 + c];
    float pz = pstats[(size_t)((h * 8 + qc) * 2 + 1) * 1024 + c];
    z += pz * expf(pm - m);
  }
  stats[h * 2048 + c] = m;
  stats[h * 2048 + 1024 + c] = 1.f / z;
}

// ------------------------------------------------------------- attn @ V (3-pass, splitK=2)
__global__ __launch_bounds__(256)
void av_kernel(const float* __restrict__ qkv, const float* __restrict__ scores,
               const float* __restrict__ stats, float* __restrict__ part) {
  __shared__ short Ph[64][40], Pl[64][40], Vh[128][40], Vl[128][40];
  const int tid = threadIdx.x;
  const int lane = tid & 63, wave = tid >> 6;

  const int lid = xcd_chunk_id(NH * 2 * 16);    // (h*2+z)*16 + y
  const int hz = lid >> 4;
  const int y = lid & 15;
  const int h = hz >> 1, z = hz & 1;
  const int bm = y << 6;

  const int wm = (wave >> 1) << 5, wn = (wave & 1) << 6;
  const int fr = lane & 15, fk = (lane >> 4) << 3;
  const float* S = scores + (size_t)h * SEQ * SEQ;
  const float* Mh = stats + h * 2048;
  const float* Rh = Mh + 1024;
  const float* V = qkv + 2 * D_MODEL + h * HD;

  floatx4 acc[2][4];
#pragma unroll
  for (int i = 0; i < 2; i++)
#pragma unroll
    for (int j = 0; j < 4; j++) acc[i][j] = (floatx4){0.f, 0.f, 0.f, 0.f};

  const int ar = tid >> 2;
  const int ac = (tid & 3) << 3;
  const int bc = tid & 127;
  const int bkq = (tid >> 7) << 4;

  for (int k0 = z * 512; k0 < z * 512 + 512; k0 += 32) {
    __syncthreads();
    {  // P = exp(s - M[k]) * rZ[k], split hi/lo
      const float* Sp = S + (size_t)(bm + ar) * SEQ + k0 + ac;
      float4 v0 = *(const float4*)(Sp);
      float4 v1 = *(const float4*)(Sp + 4);
      float t[8] = {v0.x, v0.y, v0.z, v0.w, v1.x, v1.y, v1.z, v1.w};
      float4 p0, p1;
      {
        int kk = k0 + ac;
        p0.x = expf(t[0] - Mh[kk + 0]) * Rh[kk + 0];
        p0.y = expf(t[1] - Mh[kk + 1]) * Rh[kk + 1];
        p0.z = expf(t[2] - Mh[kk + 2]) * Rh[kk + 2];
        p0.w = expf(t[3] - Mh[kk + 3]) * Rh[kk + 3];
        p1.x = expf(t[4] - Mh[kk + 4]) * Rh[kk + 4];
        p1.y = expf(t[5] - Mh[kk + 5]) * Rh[kk + 5];
        p1.z = expf(t[6] - Mh[kk + 6]) * Rh[kk + 6];
        p1.w = expf(t[7] - Mh[kk + 7]) * Rh[kk + 7];
      }
      uint4 hi, lo; split8v(p0, p1, hi, lo);
      *(uint4*)&Ph[ar][ac] = hi;
      *(uint4*)&Pl[ar][ac] = lo;
    }
    {  // V: strided gather -> [d][k]
      const float* Vp = V + (size_t)(k0 + bkq) * D3 + bc;
#pragma unroll
      for (int e = 0; e < 2; e++) {
        float4 u0, u1;
        u0.x = Vp[(size_t)(8 * e + 0) * D3]; u0.y = Vp[(size_t)(8 * e + 1) * D3];
        u0.z = Vp[(size_t)(8 * e + 2) * D3]; u0.w = Vp[(size_t)(8 * e + 3) * D3];
        u1.x = Vp[(size_t)(8 * e + 4) * D3]; u1.y = Vp[(size_t)(8 * e + 5) * D3];
        u1.z = Vp[(size_t)(8 * e + 6) * D3]; u1.w = Vp[(size_t)(8 * e + 7) * D3];
        uint4 hi, lo; split8v(u0, u1, hi, lo);
        *(uint4*)&Vh[bc][bkq + 8 * e] = hi;
        *(uint4*)&Vl[bc][bkq + 8 * e] = lo;
      }
    }
    __syncthreads();
    short8 ph[2], pl[2], vh[4], vl[4];
#pragma unroll
    for (int i = 0; i < 2; i++) {
      ph[i] = *(const short8*)&Ph[wm + (i << 4) + fr][fk];
      pl[i] = *(const short8*)&Pl[wm + (i << 4) + fr][fk];
    }
#pragma unroll
    for (int j = 0; j < 4; j++) {
      vh[j] = *(const short8*)&Vh[wn + (j << 4) + fr][fk];
      vl[j] = *(const short8*)&Vl[wn + (j << 4) + fr][fk];
    }
#pragma unroll
    for (int i = 0; i < 2; i++)
#pragma unroll
      for (int j = 0; j < 4; j++) {
        acc[i][j] = __builtin_amdgcn_mfma_f32_16x16x32_bf16(ph[i], vh[j], acc[i][j], 0, 0, 0);
        acc[i][j] = __builtin_amdgcn_mfma_f32_16x16x32_bf16(ph[i], vl[j], acc[i][j], 0, 0, 0);
        acc[i][j] = __builtin_amdgcn_mfma_f32_16x16x32_bf16(pl[i], vh[j], acc[i][j], 0, 0, 0);
      }
  }

  const int cr = (lane >> 4) << 2, cc = lane & 15;
  float* Cp = part + (size_t)z * SEQ * D_MODEL;
#pragma unroll
  for (int j = 0; j < 4; j++) {
    const int col = h * HD + wn + (j << 4) + cc;
#pragma unroll
    for (int i = 0; i < 2; i++) {
      const int row0 = bm + wm + (i << 4) + cr;
#pragma unroll
      for (int r = 0; r < 4; r++)
        Cp[(size_t)(row0 + r) * D_MODEL + col] = acc[i][j][r];
    }
  }
}

// ------------------------------------------------------------- final LN
__global__ __launch_bounds__(256)
void ln_kernel(const float* __restrict__ x, const float* __restrict__ g,
               const float* __restrict__ bb, float* __restrict__ y) {
  __shared__ float red[8];
  const int row = blockIdx.x;
  const float* xr = x + (size_t)row * D_MODEL;
  float v[6];
  float s = 0.f, sq = 0.f;
#pragma unroll
  for (int i = 0; i < 6; i++) {
    v[i] = xr[256 * i + threadIdx.x];
    s += v[i];
    sq += v[i] * v[i];
  }
#pragma unroll
  for (int off = 32; off >= 1; off >>= 1) {
    s += __shfl_down(s, off, 64);
    sq += __shfl_down(sq, off, 64);
  }
  const int lane = threadIdx.x & 63, w = threadIdx.x >> 6;
  if (lane == 0) { red[w] = s; red[4 + w] = sq; }
  __syncthreads();
  if (threadIdx.x == 0) {
    red[0] = red[0] + red[1] + red[2] + red[3];
    red[4] = red[4] + red[5] + red[6] + red[7];
  }
  __syncthreads();
  const float mu = red[0] * (1.f / D_MODEL);
  const float var = red[4] * (1.f / D_MODEL) - mu * mu;
  const float rs = rsqrtf(var + 1e-5f);
#pragma unroll
  for (int i = 0; i < 6; i++) {
    int c = 256 * i + threadIdx.x;
    y[(size_t)row * D_MODEL + c] = (v[i] - mu) * rs * g[c] + bb[c];
  }
}

// ------------------------------------------------------------- launcher
extern "C" void kernel_launch(void* const* d_in, const int* in_sizes, int n_in,
                              void* d_out, int out_size, void* d_ws, size_t ws_size,
                              hipStream_t stream) {
  (void)in_sizes; (void)n_in; (void)out_size; (void)ws_size;
  const int*   idx     = (const int*)d_in[0];
  const float* tok_emb = (const float*)d_in[2];
  const float* pos_emb = (const float*)d_in[3];
  const float* Wqkv    = (const float*)d_in[4];
  const float* bqkv    = (const float*)d_in[5];
  const float* Wo      = (const float*)d_in[6];
  const float* bo      = (const float*)d_in[7];
  const float* W1      = (const float*)d_in[8];
  const float* b1      = (const float*)d_in[9];
  const float* W2      = (const float*)d_in[10];
  const float* b2      = (const float*)d_in[11];
  const float* ln_g    = (const float*)d_in[12];
  const float* ln_b    = (const float*)d_in[13];
  const float* Wout    = (const float*)d_in[14];
  const float* bout    = (const float*)d_in[15];
  float* out = (float*)d_out;

  char* ws = (char*)d_ws;
  float* x      = (float*)(ws);                 //  6.29 MB
  float* qkv    = (float*)(ws + 6291456);       // 18.87 MB
  float* o      = (float*)(ws + 25165824);      //  6.29 MB
  float* stats  = (float*)(ws + 31457280);      //  0.10 MB
  float* pstats = (float*)(ws + 31555584);      //  0.79 MB
  float* part   = (float*)(ws + 32342016);      // 12.58 MB (2 x M*N partials)
  float* U      = (float*)(ws + 44924928);      // 50.33 MB union {scores|h1|xn}
  float* scores = U;
  float* h1     = U;
  float* xn     = U;
  const int PN = SEQ * D_MODEL;

  embed_kernel<<<6144, 256, 0, stream>>>(idx, tok_emb, pos_emb, x);

  for (int l = 0; l < NL; l++) {
    const float* wqkv = Wqkv + (size_t)l * D_MODEL * D3;
    const float* bq   = bqkv + (size_t)l * D3;
    const float* wo   = Wo   + (size_t)l * D_MODEL * D_MODEL;
    const float* bo_  = bo   + (size_t)l * D_MODEL;
    const float* w1   = W1   + (size_t)l * D_MODEL * D4;
    const float* b1_  = b1   + (size_t)l * D4;
    const float* w2   = W2   + (size_t)l * D4 * D_MODEL;
    const float* b2_  = b2   + (size_t)l * D_MODEL;

    mgemm_kernel<128, false, false, 1><<<288, 256, 0, stream>>>(
        x, wqkv, bq, nullptr, qkv, SEQ, D3, D_MODEL, 36, 8);
    scores_kernel<<<768, 256, 0, stream>>>(qkv, scores);
    colstatA_kernel<<<384, 256, 0, stream>>>(scores, pstats);
    colstatB_kernel<<<48, 256, 0, stream>>>(pstats, stats);
    av_kernel<<<384, 256, 0, stream>>>(qkv, scores, stats, part);
    combine_kernel<false, false, false><<<1536, 256, 0, stream>>>(
        part, part + PN, nullptr, nullptr, o, D_MODEL);
    mgemm_kernel<64, false, false, 2><<<384, 256, 0, stream>>>(
        o, wo, nullptr, nullptr, part, SEQ, D_MODEL, D_MODEL, 12, 16);
    combine_kernel<true, true, false><<<1536, 256, 0, stream>>>(
        part, part + PN, bo_, x, x, D_MODEL);
    mgemm_kernel<128, true, false, 1><<<384, 256, 0, stream>>>(
        x, w1, b1_, nullptr, h1, SEQ, D4, D_MODEL, 48, 8);
    mgemm_kernel<64, false, false, 2><<<384, 256, 0, stream>>>(
        h1, w2, nullptr, nullptr, part, SEQ, D_MODEL, D4, 12, 16);
    combine_kernel<true, true, false><<<1536, 256, 0, stream>>>(
        part, part + PN, b2_, x, x, D_MODEL);
  }

  ln_kernel<<<SEQ, 256, 0, stream>>>(x, ln_g, ln_b, xn);
  mgemm_kernel<64, false, false, 2><<<384, 256, 0, stream>>>(
      xn, Wout, nullptr, nullptr, part, SEQ, D_MODEL, D_MODEL, 12, 16);
  combine_kernel<true, false, false><<<1536, 256, 0, stream>>>(
      part, part + PN, bout, nullptr, out, D_MODEL);
}